// Round 5
// baseline (191.217 us; speedup 1.0000x reference)
//
#include <hip/hip_runtime.h>
#include <stdint.h>
#include <stddef.h>

// Problem constants
#define BSZ 128
#define CIN 32
#define COUT 32
#define HN 4096
#define K7 7
#define NTOT (BSZ*CIN*HN)     // 16,777,216 elements
#define NBH  (BSZ*HN)         // 524,288 (b,h) pairs

typedef __attribute__((ext_vector_type(8))) short short8;
typedef __attribute__((ext_vector_type(4))) float f32x4;

// ws layout (bytes)
#define WS_XT   0            // bf16 xt[B][H][32]            : 33,554,432 B
#define WS_WT   33554432     // bf16 wt[o][kk][c]            : 14,336 B
#define WS_NBR  33568768     // int32 nbr_pack[H][8]         : 131,072 B
#define WS_INVD 33699840     // float invd[H]                : 16,384 B
#define WS_OSTP 33716224     // float ostatp[256][64]        : 65,536 B
#define WS_OST  33781760     // float ostat[64]              : 256 B

__device__ __forceinline__ unsigned short f32_to_bf16(float f){
    union { float f; uint32_t u; } v; v.f = f;
    uint32_t u = v.u;
    return (unsigned short)((u + 0x7FFFu + ((u >> 16) & 1u)) >> 16);
}

// ---------------------------------------------------------------------------
// kinit: blocks 0..15 build neighbor table + invd + zero ostatp;
//        block 16 packs weights (bf16, A-fragment order; no std folding and
//        no bias — BatchNorm exactly cancels both).
// NOTE: harness passes integer inputs as int32 (not the reference's int64).
__global__ void kinit(const int* __restrict__ nbr,
                      const float* __restrict__ w,
                      int* __restrict__ nbr_pack,
                      float* __restrict__ invd,
                      unsigned short* __restrict__ wt,
                      float* __restrict__ ostatp){
    int t = threadIdx.x;
    if (blockIdx.x < 16){
        int h = blockIdx.x*256 + t;       // 0..4095
        #pragma unroll
        for (int j = 0; j < 4; j++) ostatp[h*4 + j] = 0.0f;   // 16384 floats
        int cnt = 0;
        int pk[8];
        #pragma unroll
        for (int j = 0; j < 6; j++){
            int iv = nbr[h*6 + j];
            if (iv >= HN) iv = HN - 1;    // safety clamp (never expected)
            if (iv >= 0) cnt++; else iv = -1;
            pk[j] = iv;
        }
        pk[6] = cnt; pk[7] = 0;
        #pragma unroll
        for (int j = 0; j < 8; j++) nbr_pack[h*8 + j] = pk[j];
        invd[h] = 1.0f / ((float)cnt + 1.0f + 1e-6f);
    } else {
        for (int i = t; i < COUT*K7*CIN; i += 256){
            int o  = i / (K7*CIN);
            int kk = (i / CIN) % K7;
            int c  = i % CIN;
            wt[i] = f32_to_bf16(w[(o*CIN + c)*K7 + kk]);
        }
    }
}

// ---------------------------------------------------------------------------
// ktrans: pure transpose x[B][C][H] f32 -> xt[B][H][C] bf16.
// grid = 128 b * 16 h-tiles(256h) = 2048 blocks of 256.
__global__ void ktrans(const float* __restrict__ x,
                       unsigned short* __restrict__ xt){
    __shared__ float tile[32][260];
    int b  = blockIdx.x >> 4;
    int h0 = (blockIdx.x & 15) << 8;
    int t  = threadIdx.x;
    #pragma unroll
    for (int l = 0; l < 8; l++){
        int linear = l*256 + t;
        int c  = linear >> 6;
        int h4 = linear & 63;
        float4 v = *(const float4*)(x + ((size_t)(b*CIN + c))*HN + h0 + h4*4);
        *(float4*)&tile[c][h4*4] = v;
    }
    __syncthreads();
    int cg = (t & 3) * 8;
    int hw = t >> 2;                      // 0..63
    #pragma unroll
    for (int r = 0; r < 4; r++){
        int h = r*64 + hw;
        alignas(16) unsigned short tmp[8];
        #pragma unroll
        for (int j = 0; j < 8; j++) tmp[j] = f32_to_bf16(tile[cg + j][h]);
        *(uint4*)(xt + ((size_t)(b*HN + h0 + h))*32 + cg) = *(const uint4*)tmp;
    }
}

// ---------------------------------------------------------------------------
__device__ __forceinline__ void gather7(short8* dst, const unsigned short* xb,
                                        int selfrow, int4 na, int4 nb, int quad){
    const short8 zero8 = {0,0,0,0,0,0,0,0};
    dst[0] = *(const short8*)(xb + (size_t)selfrow*CIN + quad*8);
    int rows[6] = {na.x, na.y, na.z, na.w, nb.x, nb.y};
    #pragma unroll
    for (int k = 0; k < 6; k++){
        int r  = rows[k];
        int rc = r < 0 ? 0 : r;
        dst[k+1] = *(const short8*)(xb + (size_t)rc*CIN + quad*8);
        if (r < 0) dst[k+1] = zero8;
    }
}

// ---------------------------------------------------------------------------
// kconv_t: gather + MFMA, software-pipelined (tbl 2 ahead, fragments 1 ahead).
// APPLY=false: accumulate BN stat partials only (no global stores).
// APPLY=true : apply BatchNorm and write final f32 out[b][o][h].
// XCD swizzle: blk&7 selects XCD-slot; each XCD sees only 16 b's -> its 4MB L2
// holds those xt slices -> gathers are L2 hits (R4-verified: FETCH 106->19MB).
// 2048 blocks; block = one b, 256 consecutive h; wave = 64 h = 4 tiles of 16.
template<bool APPLY>
__global__ __launch_bounds__(256) void kconv_t(
    const unsigned short* __restrict__ xt,
    const unsigned short* __restrict__ wt,
    const int* __restrict__ nbrp,
    const float* __restrict__ invd,
    const float* __restrict__ ostat,
    const float* __restrict__ gamma,
    const float* __restrict__ beta,
    float* __restrict__ out,
    float* __restrict__ ostatp)
{
    int lane = threadIdx.x & 63;
    int wv   = threadIdx.x >> 6;
    int n    = lane & 15;
    int quad = lane >> 4;
    int xcd  = blockIdx.x & 7;
    int j    = blockIdx.x >> 3;           // 0..255
    int b    = xcd*16 + (j >> 4);
    int hbase= ((j & 15)*4 + wv) * 64;    // this wave: h in [hbase, hbase+64)

    // A fragments (W): lane holds W[o=n+16mt][ik=kk*32 + quad*8 + jj]
    short8 af[2][K7];
    #pragma unroll
    for (int mt = 0; mt < 2; mt++){
        int o = n + 16*mt;
        #pragma unroll
        for (int kk = 0; kk < K7; kk++)
            af[mt][kk] = *(const short8*)(wt + (size_t)(o*K7 + kk)*CIN + quad*8);
    }

    // per-lane BN scale/shift for its 8 output channels (apply pass)
    float sc8[2][4], sh8[2][4];
    if (APPLY){
        #pragma unroll
        for (int mt = 0; mt < 2; mt++)
            #pragma unroll
            for (int r = 0; r < 4; r++){
                int o = mt*16 + quad*4 + r;
                float mean = ostat[o]      * (1.0f/(float)NBH);
                float var  = ostat[32 + o] * (1.0f/(float)NBH) - mean*mean;
                float s = gamma[o] * rsqrtf(var + 1e-5f);
                sc8[mt][r] = s;
                sh8[mt][r] = beta[o] - mean*s;
            }
    }

    float sacc[8]  = {0,0,0,0,0,0,0,0};
    float sacc2[8] = {0,0,0,0,0,0,0,0};
    const unsigned short* xb = xt + (size_t)b*HN*CIN;
    int hn0 = hbase + n;

    // pipeline state: tables for tiles it,it+1 ; fragments for tile it
    int4 na[2], nb[2]; float iv[2];
    short8 buf[2][K7];
    na[0] = *(const int4*)(nbrp + hn0*8);
    nb[0] = *(const int4*)(nbrp + hn0*8 + 4);
    iv[0] = invd[hn0];
    na[1] = *(const int4*)(nbrp + (hn0+16)*8);
    nb[1] = *(const int4*)(nbrp + (hn0+16)*8 + 4);
    iv[1] = invd[hn0+16];
    gather7(buf[0], xb, hn0, na[0], nb[0], quad);

    #pragma unroll
    for (int it = 0; it < 4; it++){
        int s = it & 1, o2 = s ^ 1;
        float idv = iv[s];
        if (it + 1 < 4)
            gather7(buf[o2], xb, hn0 + (it+1)*16, na[o2], nb[o2], quad);
        if (it + 2 < 4){
            na[s] = *(const int4*)(nbrp + (hn0 + (it+2)*16)*8);
            nb[s] = *(const int4*)(nbrp + (hn0 + (it+2)*16)*8 + 4);
            iv[s] = invd[hn0 + (it+2)*16];
        }
        f32x4 acc0 = {0.f,0.f,0.f,0.f};
        f32x4 acc1 = {0.f,0.f,0.f,0.f};
        #pragma unroll
        for (int kk = 0; kk < K7; kk++){
            acc0 = __builtin_amdgcn_mfma_f32_16x16x32_bf16(af[0][kk], buf[s][kk], acc0, 0, 0, 0);
            acc1 = __builtin_amdgcn_mfma_f32_16x16x32_bf16(af[1][kk], buf[s][kk], acc1, 0, 0, 0);
        }
        int hc = hbase + it*16 + n;
        // D[row=quad*4+r][col=n]; o = mt*16+quad*4+r
        #pragma unroll
        for (int mt = 0; mt < 2; mt++){
            f32x4 a = mt ? acc1 : acc0;
            #pragma unroll
            for (int r = 0; r < 4; r++){
                float v = a[r]*idv;
                if (APPLY){
                    int o = mt*16 + quad*4 + r;
                    out[((size_t)(b*COUT + o))*HN + hc] = v*sc8[mt][r] + sh8[mt][r];
                } else {
                    sacc[mt*4 + r]  += v;
                    sacc2[mt*4 + r] += v*v;
                }
            }
        }
    }

    if (!APPLY){
        // reduce BN partials over the 16 n-lanes
        #pragma unroll
        for (int bit = 1; bit < 16; bit <<= 1){
            #pragma unroll
            for (int i = 0; i < 8; i++){
                sacc[i]  += __shfl_xor(sacc[i],  bit);
                sacc2[i] += __shfl_xor(sacc2[i], bit);
            }
        }
        if (n == 0){
            int slot = blockIdx.x & 255;
            #pragma unroll
            for (int mt = 0; mt < 2; mt++)
                #pragma unroll
                for (int r = 0; r < 4; r++){
                    int o = mt*16 + quad*4 + r;
                    atomicAdd(&ostatp[slot*64 + o],      sacc[mt*4 + r]);
                    atomicAdd(&ostatp[slot*64 + 32 + o], sacc2[mt*4 + r]);
                }
        }
    }
}

// ---------------------------------------------------------------------------
// kred: fold ostatp[256][64] -> ostat[64]. One block of 256 threads.
__global__ void kred(const float* __restrict__ ostatp,
                     float* __restrict__ ostat){
    __shared__ float part[4][64];
    int t = threadIdx.x;
    int a = t & 63;
    int g = t >> 6;
    float s = 0.0f;
    #pragma unroll
    for (int j = 0; j < 64; j++)
        s += ostatp[(g*64 + j)*64 + a];
    part[g][a] = s;
    __syncthreads();
    if (t < 64)
        ostat[t] = part[0][t] + part[1][t] + part[2][t] + part[3][t];
}

// ---------------------------------------------------------------------------
extern "C" void kernel_launch(void* const* d_in, const int* in_sizes, int n_in,
                              void* d_out, int out_size, void* d_ws, size_t ws_size,
                              hipStream_t stream) {
    const float* x      = (const float*)d_in[0];
    const float* weight = (const float*)d_in[1];
    // d_in[2] = bias — exactly cancelled by BatchNorm mean subtraction
    const float* gamma  = (const float*)d_in[3];
    const float* beta   = (const float*)d_in[4];
    const int*   nbr    = (const int*)d_in[5];   // int64 in reference -> int32 from harness
    // d_in[6] = groups (==1), ignored

    char* ws = (char*)d_ws;
    unsigned short* xt    = (unsigned short*)(ws + WS_XT);
    unsigned short* wt    = (unsigned short*)(ws + WS_WT);
    int*            nbrp  = (int*)(ws + WS_NBR);
    float*          invd  = (float*)(ws + WS_INVD);
    float*          ostatp= (float*)(ws + WS_OSTP);
    float*          ostat = (float*)(ws + WS_OST);
    float*          out   = (float*)d_out;

    kinit        <<<17,   256, 0, stream>>>(nbr, weight, nbrp, invd, wt, ostatp);
    ktrans       <<<2048, 256, 0, stream>>>(x, xt);
    kconv_t<false><<<2048, 256, 0, stream>>>(xt, wt, nbrp, invd, nullptr, nullptr, nullptr, nullptr, ostatp);
    kred         <<<1,    256, 0, stream>>>(ostatp, ostat);
    kconv_t<true> <<<2048, 256, 0, stream>>>(xt, wt, nbrp, invd, ostat, gamma, beta, out, nullptr);
}